// Round 7
// baseline (189.483 us; speedup 1.0000x reference)
//
#include <hip/hip_runtime.h>

typedef _Float16 f16x8 __attribute__((ext_vector_type(8)));
typedef _Float16 f16x4 __attribute__((ext_vector_type(4)));
typedef float    f32x4 __attribute__((ext_vector_type(4)));

// Split barrier: LDS-visibility only. Does NOT drain vmcnt (global loads /
// stores stay in flight across it) -- unlike __syncthreads(), which emits
// s_waitcnt vmcnt(0) lgkmcnt(0) and serializes the pipeline on store acks.
// sched_barrier(0) fences per rule #18 (compiler may hoist past inline asm).
__device__ __forceinline__ void lds_barrier() {
    asm volatile("s_waitcnt lgkmcnt(0)" ::: "memory");
    __builtin_amdgcn_sched_barrier(0);
    __builtin_amdgcn_s_barrier();
    __builtin_amdgcn_sched_barrier(0);
}

// ===========================================================================
// K1: QKV 1x1-conv projection, persistent double-buffered MFMA GEMM.
//   D[px, o] = sum_c x[c,px] * W[o,c] + b[o],  o in [0,192) = {Q|K|V}x64.
// Grid 512 = 2 blocks/CU persistent (LDS 56KB). Structure as R6; the ONLY
// change: per-tile __syncthreads() -> lds_barrier(), so the 24 HBM stores
// per wave per tile drain in the background instead of serializing each
// iteration (R6 counters: 2.7 TB/s with all pipes idle = barrier drain).
// ===========================================================================
#define W_OFF  0       // 24576 B : w [192o][64c] fp16, row 128B, swz (orow&7)<<4
#define XA_OFF 24576   // 16384 B : x tile buf A fp16 [64c][128px], swz ((c>>3)&7)<<4
#define XB_OFF 40960   // 16384 B : x tile buf B

__global__ __launch_bounds__(256, 2) void proj_qkv_mfma(
    const float* __restrict__ x,
    const float* __restrict__ wq, const float* __restrict__ bq,
    const float* __restrict__ wk, const float* __restrict__ bk,
    const float* __restrict__ wv, const float* __restrict__ bv,
    _Float16* __restrict__ Qh, _Float16* __restrict__ Kh, _Float16* __restrict__ Vh)
{
    __shared__ __align__(16) unsigned char lds[57344];

    const int tid  = threadIdx.x;
    const int lane = tid & 63;
    const int wid  = tid >> 6;
    const int q4   = lane >> 4;
    const int l15  = lane & 15;

    const int pg0  = blockIdx.x << 10;        // 1024 px per block
    const int bb   = pg0 >> 16;               // batch (1024 divides 65536)
    const int pix0 = pg0 & 65535;
    const float* xb = x + ((size_t)bb << 22); // bb*64*65536

    // staging geometry (one 128-px tile): thread covers 8 float4 slots
    const int sc = tid >> 5;                  // c row base (8 per it)
    const int sslot = tid & 31;               // px = sslot*4

    // ---- bias preload ----
    float bld[12];
#pragma unroll
    for (int ot = 0; ot < 12; ++ot) {
        const int mat = ot >> 2;
        const float* bs = (mat == 0) ? bq : (mat == 1) ? bk : bv;
        bld[ot] = bs[((ot & 3) << 4) + l15];
    }

    // ---- stage ALL weights once: [192][64] f32 -> fp16 LDS ----
#pragma unroll
    for (int it = 0; it < 12; ++it) {
        const int idx  = (it << 8) + tid;      // float4 slots
        const int orow = idx >> 4;
        const int s    = idx & 15;             // c = s*4
        const int mat  = orow >> 6;
        const float* wsrc = (mat == 0) ? wq : (mat == 1) ? wk : wv;
        const f32x4 v = *(const f32x4*)(wsrc + ((orow & 63) << 6) + (s << 2));
        f16x4 h;
#pragma unroll
        for (int j = 0; j < 4; ++j) h[j] = (_Float16)v[j];
        const int a = ((orow << 7) + (s << 3)) ^ ((orow & 7) << 4);
        *(f16x4*)(lds + W_OFF + a) = h;
    }

    // ---- prologue: stage tile 0 into buf A ----
    {
        f32x4 xv[8];
#pragma unroll
        for (int it = 0; it < 8; ++it) {
            const int c = (it << 3) + sc;
            xv[it] = *(const f32x4*)(xb + ((size_t)c << 16) + pix0 + (sslot << 2));
        }
#pragma unroll
        for (int it = 0; it < 8; ++it) {
            const int c = (it << 3) + sc;
            f16x4 h;
#pragma unroll
            for (int j = 0; j < 4; ++j) h[j] = (_Float16)xv[it][j];
            const int a = ((c << 8) + (sslot << 3)) ^ (((c >> 3) & 7) << 4);
            *(f16x4*)(lds + XA_OFF + a) = h;
        }
    }
    __syncthreads();                           // one-time full drain is fine

    const int wpx = wid << 5;                  // wave px base (32 px/wave)

    for (int t = 0; t < 8; ++t) {
        const int bufo = (t & 1) ? XB_OFF : XA_OFF;
        const int nbufo = (t & 1) ? XA_OFF : XB_OFF;
        const int pixT = pix0 + (t << 7);

        // ---- issue tile t+1 loads NOW (in flight during compute) ----
        f32x4 xv[8];
        if (t < 7) {
            const int pixN = pixT + 128;
#pragma unroll
            for (int it = 0; it < 8; ++it) {
                const int c = (it << 3) + sc;
                xv[it] = *(const f32x4*)(xb + ((size_t)c << 16) + pixN + (sslot << 2));
            }
        }

        // ---- compute tile t ----
        // A fragments: lane l15 = px, k = c (u16 gathers, lgkmcnt only)
        f16x8 af[2][2];
#pragma unroll
        for (int pt = 0; pt < 2; ++pt)
#pragma unroll
            for (int kc = 0; kc < 2; ++kc) {
                const int px = wpx + (pt << 4) + l15;
                f16x8 a;
#pragma unroll
                for (int j = 0; j < 8; ++j) {
                    const int c  = (kc << 5) + (q4 << 3) + j;
                    const int ad = ((c << 8) + (px << 1)) ^ (((c >> 3) & 7) << 4);
                    a[j] = *(const _Float16*)(lds + bufo + ad);
                }
                af[pt][kc] = a;
            }

        // ot loop: B from LDS, MFMA, packed 8B stores (background drain)
#pragma unroll
        for (int ot = 0; ot < 12; ++ot) {
            const int mat = ot >> 2;
            const int row = (ot << 4) + l15;   // B lane l15 = o col
            const int rsw = (row & 7) << 4;
            const f16x8 bf0 = *(const f16x8*)(lds + W_OFF + (((row << 7) + (q4 << 4)) ^ rsw));
            const f16x8 bf1 = *(const f16x8*)(lds + W_OFF + (((row << 7) + 64 + (q4 << 4)) ^ rsw));
            _Float16* ob = (mat == 0) ? Qh : (mat == 1) ? Kh : Vh;
            const int r64 = ((ot & 3) << 4) + l15;
            const size_t obase = ((size_t)((bb << 6) + r64) << 16) + pixT + wpx + (q4 << 2);
#pragma unroll
            for (int pt = 0; pt < 2; ++pt) {
                f32x4 acc = { bld[ot], bld[ot], bld[ot], bld[ot] };
                acc = __builtin_amdgcn_mfma_f32_16x16x32_f16(af[pt][0], bf0, acc, 0, 0, 0);
                acc = __builtin_amdgcn_mfma_f32_16x16x32_f16(af[pt][1], bf1, acc, 0, 0, 0);
                f16x4 h;
#pragma unroll
                for (int r = 0; r < 4; ++r) h[r] = (_Float16)acc[r];
                *(f16x4*)(ob + obase + (pt << 4)) = h;
            }
        }

        // ---- cvt + ds_write tile t+1 into other buffer ----
        if (t < 7) {
#pragma unroll
            for (int it = 0; it < 8; ++it) {
                const int c = (it << 3) + sc;
                f16x4 h;
#pragma unroll
                for (int j = 0; j < 4; ++j) h[j] = (_Float16)xv[it][j];
                const int a = ((c << 8) + (sslot << 3)) ^ (((c >> 3) & 7) << 4);
                *(f16x4*)(lds + nbufo + a) = h;
            }
        }
        lds_barrier();                         // NO vmcnt drain (the fix)
    }
}

// ===========================================================================
// K2: fused attention per (b,c). 16 waves; wave (wr,wc) owns a 64x64 att tile.
// Depth-2 register prefetch for Q/K and V; V prefetch before softmax.
// Round-6 change: ALL __syncthreads() -> lds_barrier() (no vmcnt drains;
// prefetch loads stay in flight across barriers; 16-wave convoy relieved).
// ===========================================================================
#define P_OFF 0        // 131072 B : P fp16 [256][256]
#define B_OFF 131072   //  16384 B : Q chunk | softmax partials | Vt chunk
#define K_OFF 147456   //  16384 B : K chunk

__global__ __launch_bounds__(1024, 4) void attn_rowsm(
    const _Float16* __restrict__ Qh, const _Float16* __restrict__ Kh,
    const _Float16* __restrict__ Vh, const float* __restrict__ gamma,
    float* __restrict__ out)
{
    __shared__ __align__(16) unsigned char lds[163840];

    const int tid  = threadIdx.x;
    const int lane = tid & 63;
    const int wid  = tid >> 6;
    const int wr   = wid >> 2;
    const int wc   = wid & 3;
    const int q4   = lane >> 4;
    const int l15  = lane & 15;
    const size_t base = (size_t)blockIdx.x << 16;    // (b*64+c) * 65536

    const f32x4 fzero = {0.f, 0.f, 0.f, 0.f};
    f32x4 acc[4][4];
#pragma unroll
    for (int i = 0; i < 4; ++i)
#pragma unroll
        for (int j = 0; j < 4; ++j) acc[i][j] = fzero;

    // ---------------- phase 1: att = Q K^T (depth-2 prefetch) --------------
    const int sh = tid >> 2;                 // staging row 0..255
    const int ss = tid & 3;                  // 16B slot 0..3
    const int soff = ((sh << 6) + (ss << 4)) ^ ((sh & 7) << 4);
    const size_t sg = base + (size_t)sh * 256 + ss * 8;

    auto qk_compute = [&]() {
        f16x8 bf[4];
#pragma unroll
        for (int ni = 0; ni < 4; ++ni) {
            const int g = (wc << 6) + (ni << 4) + l15;
            bf[ni] = *(const f16x8*)(lds + K_OFF + (((g << 6) + (q4 << 4)) ^ ((g & 7) << 4)));
        }
#pragma unroll
        for (int mi = 0; mi < 4; ++mi) {
            const int h = (wr << 6) + (mi << 4) + l15;
            const f16x8 afr = *(const f16x8*)(lds + B_OFF + (((h << 6) + (q4 << 4)) ^ ((h & 7) << 4)));
#pragma unroll
            for (int ni = 0; ni < 4; ++ni)
                acc[mi][ni] = __builtin_amdgcn_mfma_f32_16x16x32_f16(afr, bf[ni], acc[mi][ni], 0, 0, 0);
        }
    };

    uint4 qdA = *(const uint4*)(Qh + sg);
    uint4 kdA = *(const uint4*)(Kh + sg);
    uint4 qdB = *(const uint4*)(Qh + sg + 32);
    uint4 kdB = *(const uint4*)(Kh + sg + 32);

    for (int kc = 0; kc < 256; kc += 64) {
        lds_barrier();
        *(uint4*)(lds + B_OFF + soff) = qdA;
        *(uint4*)(lds + K_OFF + soff) = kdA;
        if (kc < 192) {
            qdA = *(const uint4*)(Qh + sg + kc + 64);
            kdA = *(const uint4*)(Kh + sg + kc + 64);
        }
        lds_barrier();
        qk_compute();

        lds_barrier();
        *(uint4*)(lds + B_OFF + soff) = qdB;
        *(uint4*)(lds + K_OFF + soff) = kdB;
        if (kc < 192) {
            qdB = *(const uint4*)(Qh + sg + kc + 96);
            kdB = *(const uint4*)(Kh + sg + kc + 96);
        }
        lds_barrier();
        qk_compute();
    }

    // V chunks 0,1 prefetch: issue NOW so the softmax phase hides the latency
    const int gg = tid >> 5;                 // g within chunk 0..31
    const int wo = tid & 31;                 // w octet
    const size_t vg = base + (size_t)gg * 256 + wo * 8;
    uint4 vdA = *(const uint4*)(Vh + vg);
    uint4 vdB = *(const uint4*)(Vh + vg + 32 * 256);

    // ---------------- phase 2: diag add + softmax over h ----------------
    const float g_sig = 1.0f / (1.0f + __expf(-gamma[0]));
    if (wr == wc) {                          // diagonal tiles: h==g
        const int rn = l15 - (q4 << 2);
        if (rn >= 0 && rn < 4) {
#pragma unroll
            for (int mi = 0; mi < 4; ++mi) acc[mi][mi][rn] += g_sig;
        }
    }

    float* red = (float*)(lds + B_OFF);      // [4][256] partials
    float cmx[4], cinv[4];

    lds_barrier();                           // phase-1 LDS now dead
#pragma unroll
    for (int ni = 0; ni < 4; ++ni) {
        float m = -3.0e38f;
#pragma unroll
        for (int mi = 0; mi < 4; ++mi)
#pragma unroll
            for (int r = 0; r < 4; ++r) m = fmaxf(m, acc[mi][ni][r]);
        m = fmaxf(m, __shfl_xor(m, 16));
        m = fmaxf(m, __shfl_xor(m, 32));
        cmx[ni] = m;
        if (q4 == 0) red[wr * 256 + (wc << 6) + (ni << 4) + l15] = m;
    }
    lds_barrier();
#pragma unroll
    for (int ni = 0; ni < 4; ++ni) {
        const int col = (wc << 6) + (ni << 4) + l15;
        float m = red[col];
        m = fmaxf(m, red[256 + col]);
        m = fmaxf(m, red[512 + col]);
        m = fmaxf(m, red[768 + col]);
        cmx[ni] = m;
    }
    lds_barrier();                           // maxes consumed; reuse red for sums
#pragma unroll
    for (int ni = 0; ni < 4; ++ni) {
        float s = 0.f;
#pragma unroll
        for (int mi = 0; mi < 4; ++mi)
#pragma unroll
            for (int r = 0; r < 4; ++r) {
                const float e = __expf(acc[mi][ni][r] - cmx[ni]);
                acc[mi][ni][r] = e;
                s += e;
            }
        s += __shfl_xor(s, 16);
        s += __shfl_xor(s, 32);
        if (q4 == 0) red[wr * 256 + (wc << 6) + (ni << 4) + l15] = s;
    }
    lds_barrier();
#pragma unroll
    for (int ni = 0; ni < 4; ++ni) {
        const int col = (wc << 6) + (ni << 4) + l15;
        cinv[ni] = 1.0f / (red[col] + red[256 + col] + red[512 + col] + red[768 + col]);
    }

    // write normalized P to LDS (fp16, swizzled [256][256])
#pragma unroll
    for (int mi = 0; mi < 4; ++mi) {
        const int hbase = (wr << 6) + (mi << 4) + (q4 << 2);
#pragma unroll
        for (int r = 0; r < 4; ++r) {
            const int h  = hbase + r;
            const int hb = h << 9;           // h*512 bytes
            const int sw = (h & 7) << 4;
#pragma unroll
            for (int ni = 0; ni < 4; ++ni) {
                const int g = (wc << 6) + (ni << 4) + l15;
                *(_Float16*)(lds + P_OFF + ((hb + (g << 1)) ^ sw)) =
                    (_Float16)(acc[mi][ni][r] * cinv[ni]);
            }
        }
    }

    // ---------------- phase 3: out = P V (depth-2 prefetch) ----------------
#pragma unroll
    for (int i = 0; i < 4; ++i)
#pragma unroll
        for (int j = 0; j < 4; ++j) acc[i][j] = fzero;

    auto v_write = [&](const uint4& vd) {
        const _Float16* ve = (const _Float16*)&vd;
#pragma unroll
        for (int j = 0; j < 8; ++j) {
            const int w  = (wo << 3) + j;
            const int fw = ((w & 7) ^ ((w >> 3) & 7)) << 4;
            *(_Float16*)(lds + B_OFF + (((w << 6) + (gg << 1)) ^ fw)) = ve[j];
        }
    };
    auto pv_compute = [&](int gc) {
        f16x8 bf[4];
#pragma unroll
        for (int ni = 0; ni < 4; ++ni) {
            const int w  = (wc << 6) + (ni << 4) + l15;
            const int fw = ((w & 7) ^ ((w >> 3) & 7)) << 4;
            bf[ni] = *(const f16x8*)(lds + B_OFF + (((w << 6) + (q4 << 4)) ^ fw));
        }
#pragma unroll
        for (int mi = 0; mi < 4; ++mi) {
            const int h = (wr << 6) + (mi << 4) + l15;
            const f16x8 afr = *(const f16x8*)(lds + P_OFF +
                (((h << 9) + ((gc + (q4 << 3)) << 1)) ^ ((h & 7) << 4)));
#pragma unroll
            for (int ni = 0; ni < 4; ++ni)
                acc[mi][ni] = __builtin_amdgcn_mfma_f32_16x16x32_f16(afr, bf[ni], acc[mi][ni], 0, 0, 0);
        }
    };

    for (int gc = 0; gc < 256; gc += 64) {
        lds_barrier();                       // P written / prior Vt reads done
        v_write(vdA);
        if (gc < 192) vdA = *(const uint4*)(Vh + vg + (size_t)(gc + 64) * 256);
        lds_barrier();
        pv_compute(gc);

        lds_barrier();
        v_write(vdB);
        if (gc < 192) vdB = *(const uint4*)(Vh + vg + (size_t)(gc + 96) * 256);
        lds_barrier();
        pv_compute(gc + 32);
    }

    // ---------------- store out (fp32) ----------------
    float* op = out + base;
#pragma unroll
    for (int mi = 0; mi < 4; ++mi) {
#pragma unroll
        for (int r = 0; r < 4; ++r) {
            const int h = (wr << 6) + (mi << 4) + (q4 << 2) + r;
#pragma unroll
            for (int ni = 0; ni < 4; ++ni) {
                const int w = (wc << 6) + (ni << 4) + l15;
                op[(h << 8) + w] = acc[mi][ni][r];
            }
        }
    }
}

// ---------------------------------------------------------------------------
extern "C" void kernel_launch(void* const* d_in, const int* in_sizes, int n_in,
                              void* d_out, int out_size, void* d_ws, size_t ws_size,
                              hipStream_t stream) {
    const float* x     = (const float*)d_in[0];
    const float* wq    = (const float*)d_in[1];
    const float* bq    = (const float*)d_in[2];
    const float* wk    = (const float*)d_in[3];
    const float* bk    = (const float*)d_in[4];
    const float* wv    = (const float*)d_in[5];
    const float* bv    = (const float*)d_in[6];
    const float* gamma = (const float*)d_in[7];
    float* out = (float*)d_out;

    // workspace: Q,K,V fp16, each 512*65536 elements = 64 MiB -> 192 MiB total
    _Float16* Qh = (_Float16*)d_ws;
    _Float16* Kh = Qh + (size_t)512 * 65536;
    _Float16* Vh = Kh + (size_t)512 * 65536;

    proj_qkv_mfma<<<512, 256, 0, stream>>>(x, wq, bq, wk, bk, wv, bv, Qh, Kh, Vh);
    attn_rowsm<<<512, 1024, 0, stream>>>(Qh, Kh, Vh, gamma, out);
}

// Round 8
// 163.842 us; speedup vs baseline: 1.1565x; 1.1565x over previous
//
#include <hip/hip_runtime.h>

typedef _Float16 f16x8 __attribute__((ext_vector_type(8)));
typedef _Float16 f16x4 __attribute__((ext_vector_type(4)));
typedef float    f32x4 __attribute__((ext_vector_type(4)));

// LDS-visibility-only barrier (no vmcnt drain): global stores issued before it
// keep draining in the background. Required for the K1 round pipeline.
__device__ __forceinline__ void lds_barrier() {
    asm volatile("s_waitcnt lgkmcnt(0)" ::: "memory");
    __builtin_amdgcn_sched_barrier(0);
    __builtin_amdgcn_s_barrier();
    __builtin_amdgcn_sched_barrier(0);
}

// ===========================================================================
// K1: QKV 1x1-conv projection, persistent double-buffered MFMA GEMM with
// LDS-transpose epilogue for fully-coalesced stores.
//   D[px, o] = sum_c x[c,px] * W[o,c] + b[o],  o in [0,192) = {Q|K|V}x64.
// R2-R7 invariant diagnosed: every variant stored 16 scattered 32B segments
// per wave instruction (o varies across lanes) and pinned at 2.3-2.7 TB/s.
// Fix: MFMA results -> OUT LDS buffer (swizzled) -> bulk store phase where
// each wave instruction writes 4 x 256B CONTIGUOUS segments (uint4/lane).
// Grid 512 = 2 blocks/CU (LDS 80KB exactly). 8 tiles x 128 px per block.
// ===========================================================================
#define W_OFF   0      // 24576 B : w [192o][64c] fp16, row 128B, swz (orow&7)<<4
#define XA_OFF  24576  // 16384 B : x tile buf A fp16 [64c][128px], swz ((c>>3)&7)<<4
#define XB_OFF  40960  // 16384 B : x tile buf B
#define OUT_OFF 57344  // 24576 B : out [96oo][128px] fp16, swz (oo&7)<<4

__global__ __launch_bounds__(256, 2) void proj_qkv_mfma(
    const float* __restrict__ x,
    const float* __restrict__ wq, const float* __restrict__ bq,
    const float* __restrict__ wk, const float* __restrict__ bk,
    const float* __restrict__ wv, const float* __restrict__ bv,
    _Float16* __restrict__ Qh, _Float16* __restrict__ Kh, _Float16* __restrict__ Vh)
{
    __shared__ __align__(16) unsigned char lds[81920];

    const int tid  = threadIdx.x;
    const int lane = tid & 63;
    const int wid  = tid >> 6;
    const int q4   = lane >> 4;
    const int l15  = lane & 15;

    const int pg0  = blockIdx.x << 10;        // 1024 px per block
    const int bb   = pg0 >> 16;               // batch (1024 divides 65536)
    const int pix0 = pg0 & 65535;
    const float* xb = x + ((size_t)bb << 22); // bb*64*65536

    // staging geometry (one 128-px tile): thread covers 8 float4 slots
    const int sc = tid >> 5;                  // c row base (8 per it)
    const int sslot = tid & 31;               // px = sslot*4

    // ---- bias preload ----
    float bld[12];
#pragma unroll
    for (int ot = 0; ot < 12; ++ot) {
        const int mat = ot >> 2;
        const float* bs = (mat == 0) ? bq : (mat == 1) ? bk : bv;
        bld[ot] = bs[((ot & 3) << 4) + l15];
    }

    // ---- stage ALL weights once: [192][64] f32 -> fp16 LDS ----
#pragma unroll
    for (int it = 0; it < 12; ++it) {
        const int idx  = (it << 8) + tid;      // float4 slots
        const int orow = idx >> 4;
        const int s    = idx & 15;             // c = s*4
        const int mat  = orow >> 6;
        const float* wsrc = (mat == 0) ? wq : (mat == 1) ? wk : wv;
        const f32x4 v = *(const f32x4*)(wsrc + ((orow & 63) << 6) + (s << 2));
        f16x4 h;
#pragma unroll
        for (int j = 0; j < 4; ++j) h[j] = (_Float16)v[j];
        const int a = ((orow << 7) + (s << 3)) ^ ((orow & 7) << 4);
        *(f16x4*)(lds + W_OFF + a) = h;
    }

    // ---- prologue: stage tile 0 into buf A ----
    {
        f32x4 xv[8];
#pragma unroll
        for (int it = 0; it < 8; ++it) {
            const int c = (it << 3) + sc;
            xv[it] = *(const f32x4*)(xb + ((size_t)c << 16) + pix0 + (sslot << 2));
        }
#pragma unroll
        for (int it = 0; it < 8; ++it) {
            const int c = (it << 3) + sc;
            f16x4 h;
#pragma unroll
            for (int j = 0; j < 4; ++j) h[j] = (_Float16)xv[it][j];
            const int a = ((c << 8) + (sslot << 3)) ^ (((c >> 3) & 7) << 4);
            *(f16x4*)(lds + XA_OFF + a) = h;
        }
    }
    __syncthreads();                           // one-time full drain is fine

    const int wpx = wid << 5;                  // wave px base (32 px/wave)

    for (int t = 0; t < 8; ++t) {
        const int bufo = (t & 1) ? XB_OFF : XA_OFF;
        const int nbufo = (t & 1) ? XA_OFF : XB_OFF;
        const int pixT = pix0 + (t << 7);

        // ---- issue tile t+1 loads NOW (in flight during compute) ----
        f32x4 xv[8];
        if (t < 7) {
            const int pixN = pixT + 128;
#pragma unroll
            for (int it = 0; it < 8; ++it) {
                const int c = (it << 3) + sc;
                xv[it] = *(const f32x4*)(xb + ((size_t)c << 16) + pixN + (sslot << 2));
            }
        }

        // ---- A fragments: lane l15 = px, k = c (u16 gathers, lgkm only) ----
        f16x8 af[2][2];
#pragma unroll
        for (int pt = 0; pt < 2; ++pt)
#pragma unroll
            for (int kc = 0; kc < 2; ++kc) {
                const int px = wpx + (pt << 4) + l15;
                f16x8 a;
#pragma unroll
                for (int j = 0; j < 8; ++j) {
                    const int c  = (kc << 5) + (q4 << 3) + j;
                    const int ad = ((c << 8) + (px << 1)) ^ (((c >> 3) & 7) << 4);
                    a[j] = *(const _Float16*)(lds + bufo + ad);
                }
                af[pt][kc] = a;
            }

        // ---- 2 rounds x 6 o-tiles: MFMA -> OUT LDS -> coalesced bulk store ----
#pragma unroll
        for (int rd = 0; rd < 2; ++rd) {
            if (rd) lds_barrier();             // round-0 bulk-store reads done
#pragma unroll
            for (int ot6 = 0; ot6 < 6; ++ot6) {
                const int ot  = rd * 6 + ot6;
                const int row = (ot << 4) + l15;   // W row (B lane l15 = o col)
                const int rsw = (row & 7) << 4;
                const f16x8 bf0 = *(const f16x8*)(lds + W_OFF + (((row << 7) + (q4 << 4)) ^ rsw));
                const f16x8 bf1 = *(const f16x8*)(lds + W_OFF + (((row << 7) + 64 + (q4 << 4)) ^ rsw));
                const int oo  = (ot6 << 4) + l15;  // OUT row
                const int osw = (oo & 7) << 4;
#pragma unroll
                for (int pt = 0; pt < 2; ++pt) {
                    f32x4 acc = { bld[ot], bld[ot], bld[ot], bld[ot] };
                    acc = __builtin_amdgcn_mfma_f32_16x16x32_f16(af[pt][0], bf0, acc, 0, 0, 0);
                    acc = __builtin_amdgcn_mfma_f32_16x16x32_f16(af[pt][1], bf1, acc, 0, 0, 0);
                    f16x4 h;
#pragma unroll
                    for (int r = 0; r < 4; ++r) h[r] = (_Float16)acc[r];
                    const int px = wpx + (pt << 4) + (q4 << 2);
                    *(f16x4*)(lds + OUT_OFF + (((oo << 8) + (px << 1)) ^ osw)) = h;
                }
            }
            lds_barrier();                     // all OUT writes visible

            // bulk store: wave instr = 4 rows x 256B contiguous (uint4/lane)
#pragma unroll
            for (int it = 0; it < 6; ++it) {
                const int idx = (it << 8) + tid;
                const int oo  = idx >> 4;          // 0..95
                const int sl  = idx & 15;          // 16B slot (8 px)
                const uint4 vst = *(const uint4*)(lds + OUT_OFF +
                    (((oo << 8) + (sl << 4)) ^ ((oo & 7) << 4)));
                const int ot  = rd * 6 + (oo >> 4);
                const int mat = ot >> 2;
                _Float16* ob = (mat == 0) ? Qh : (mat == 1) ? Kh : Vh;
                const int orow = ((ot & 3) << 4) + (oo & 15);
                *(uint4*)(ob + (((size_t)((bb << 6) + orow)) << 16) + pixT + (sl << 3)) = vst;
            }
        }

        // ---- cvt + ds_write tile t+1 into other x buffer ----
        if (t < 7) {
#pragma unroll
            for (int it = 0; it < 8; ++it) {
                const int c = (it << 3) + sc;
                f16x4 h;
#pragma unroll
                for (int j = 0; j < 4; ++j) h[j] = (_Float16)xv[it][j];
                const int a = ((c << 8) + (sslot << 3)) ^ (((c >> 3) & 7) << 4);
                *(f16x4*)(lds + nbufo + a) = h;
            }
        }
        lds_barrier();                         // x swap + OUT reads complete
    }
}

// ===========================================================================
// K2: fused attention per (b,c). 16 waves; wave (wr,wc) owns a 64x64 att tile.
// Depth-2 register prefetch for Q/K and V; V prefetch before softmax.
// Reverted to __syncthreads() (R6 form, best measured ~74us): lds_barrier's
// sched fences cost ~8us here (R7).
// ===========================================================================
#define P_OFF 0        // 131072 B : P fp16 [256][256]
#define B_OFF 131072   //  16384 B : Q chunk | softmax partials | Vt chunk
#define K_OFF 147456   //  16384 B : K chunk

__global__ __launch_bounds__(1024, 4) void attn_rowsm(
    const _Float16* __restrict__ Qh, const _Float16* __restrict__ Kh,
    const _Float16* __restrict__ Vh, const float* __restrict__ gamma,
    float* __restrict__ out)
{
    __shared__ __align__(16) unsigned char lds[163840];

    const int tid  = threadIdx.x;
    const int lane = tid & 63;
    const int wid  = tid >> 6;
    const int wr   = wid >> 2;
    const int wc   = wid & 3;
    const int q4   = lane >> 4;
    const int l15  = lane & 15;
    const size_t base = (size_t)blockIdx.x << 16;    // (b*64+c) * 65536

    const f32x4 fzero = {0.f, 0.f, 0.f, 0.f};
    f32x4 acc[4][4];
#pragma unroll
    for (int i = 0; i < 4; ++i)
#pragma unroll
        for (int j = 0; j < 4; ++j) acc[i][j] = fzero;

    // ---------------- phase 1: att = Q K^T (depth-2 prefetch) --------------
    const int sh = tid >> 2;                 // staging row 0..255
    const int ss = tid & 3;                  // 16B slot 0..3
    const int soff = ((sh << 6) + (ss << 4)) ^ ((sh & 7) << 4);
    const size_t sg = base + (size_t)sh * 256 + ss * 8;

    auto qk_compute = [&]() {
        f16x8 bf[4];
#pragma unroll
        for (int ni = 0; ni < 4; ++ni) {
            const int g = (wc << 6) + (ni << 4) + l15;
            bf[ni] = *(const f16x8*)(lds + K_OFF + (((g << 6) + (q4 << 4)) ^ ((g & 7) << 4)));
        }
#pragma unroll
        for (int mi = 0; mi < 4; ++mi) {
            const int h = (wr << 6) + (mi << 4) + l15;
            const f16x8 afr = *(const f16x8*)(lds + B_OFF + (((h << 6) + (q4 << 4)) ^ ((h & 7) << 4)));
#pragma unroll
            for (int ni = 0; ni < 4; ++ni)
                acc[mi][ni] = __builtin_amdgcn_mfma_f32_16x16x32_f16(afr, bf[ni], acc[mi][ni], 0, 0, 0);
        }
    };

    uint4 qdA = *(const uint4*)(Qh + sg);
    uint4 kdA = *(const uint4*)(Kh + sg);
    uint4 qdB = *(const uint4*)(Qh + sg + 32);
    uint4 kdB = *(const uint4*)(Kh + sg + 32);

    for (int kc = 0; kc < 256; kc += 64) {
        __syncthreads();
        *(uint4*)(lds + B_OFF + soff) = qdA;
        *(uint4*)(lds + K_OFF + soff) = kdA;
        if (kc < 192) {
            qdA = *(const uint4*)(Qh + sg + kc + 64);
            kdA = *(const uint4*)(Kh + sg + kc + 64);
        }
        __syncthreads();
        qk_compute();

        __syncthreads();
        *(uint4*)(lds + B_OFF + soff) = qdB;
        *(uint4*)(lds + K_OFF + soff) = kdB;
        if (kc < 192) {
            qdB = *(const uint4*)(Qh + sg + kc + 96);
            kdB = *(const uint4*)(Kh + sg + kc + 96);
        }
        __syncthreads();
        qk_compute();
    }

    // V chunks 0,1 prefetch: issue NOW so the softmax phase hides the latency
    const int gg = tid >> 5;                 // g within chunk 0..31
    const int wo = tid & 31;                 // w octet
    const size_t vg = base + (size_t)gg * 256 + wo * 8;
    uint4 vdA = *(const uint4*)(Vh + vg);
    uint4 vdB = *(const uint4*)(Vh + vg + 32 * 256);

    // ---------------- phase 2: diag add + softmax over h ----------------
    const float g_sig = 1.0f / (1.0f + __expf(-gamma[0]));
    if (wr == wc) {                          // diagonal tiles: h==g
        const int rn = l15 - (q4 << 2);
        if (rn >= 0 && rn < 4) {
#pragma unroll
            for (int mi = 0; mi < 4; ++mi) acc[mi][mi][rn] += g_sig;
        }
    }

    float* red = (float*)(lds + B_OFF);      // [4][256] partials
    float cmx[4], cinv[4];

    __syncthreads();                         // phase-1 LDS now dead
#pragma unroll
    for (int ni = 0; ni < 4; ++ni) {
        float m = -3.0e38f;
#pragma unroll
        for (int mi = 0; mi < 4; ++mi)
#pragma unroll
            for (int r = 0; r < 4; ++r) m = fmaxf(m, acc[mi][ni][r]);
        m = fmaxf(m, __shfl_xor(m, 16));
        m = fmaxf(m, __shfl_xor(m, 32));
        cmx[ni] = m;
        if (q4 == 0) red[wr * 256 + (wc << 6) + (ni << 4) + l15] = m;
    }
    __syncthreads();
#pragma unroll
    for (int ni = 0; ni < 4; ++ni) {
        const int col = (wc << 6) + (ni << 4) + l15;
        float m = red[col];
        m = fmaxf(m, red[256 + col]);
        m = fmaxf(m, red[512 + col]);
        m = fmaxf(m, red[768 + col]);
        cmx[ni] = m;
    }
    __syncthreads();                         // maxes consumed; reuse red for sums
#pragma unroll
    for (int ni = 0; ni < 4; ++ni) {
        float s = 0.f;
#pragma unroll
        for (int mi = 0; mi < 4; ++mi)
#pragma unroll
            for (int r = 0; r < 4; ++r) {
                const float e = __expf(acc[mi][ni][r] - cmx[ni]);
                acc[mi][ni][r] = e;
                s += e;
            }
        s += __shfl_xor(s, 16);
        s += __shfl_xor(s, 32);
        if (q4 == 0) red[wr * 256 + (wc << 6) + (ni << 4) + l15] = s;
    }
    __syncthreads();
#pragma unroll
    for (int ni = 0; ni < 4; ++ni) {
        const int col = (wc << 6) + (ni << 4) + l15;
        cinv[ni] = 1.0f / (red[col] + red[256 + col] + red[512 + col] + red[768 + col]);
    }

    // write normalized P to LDS (fp16, swizzled [256][256])
#pragma unroll
    for (int mi = 0; mi < 4; ++mi) {
        const int hbase = (wr << 6) + (mi << 4) + (q4 << 2);
#pragma unroll
        for (int r = 0; r < 4; ++r) {
            const int h  = hbase + r;
            const int hb = h << 9;           // h*512 bytes
            const int sw = (h & 7) << 4;
#pragma unroll
            for (int ni = 0; ni < 4; ++ni) {
                const int g = (wc << 6) + (ni << 4) + l15;
                *(_Float16*)(lds + P_OFF + ((hb + (g << 1)) ^ sw)) =
                    (_Float16)(acc[mi][ni][r] * cinv[ni]);
            }
        }
    }

    // ---------------- phase 3: out = P V (depth-2 prefetch) ----------------
#pragma unroll
    for (int i = 0; i < 4; ++i)
#pragma unroll
        for (int j = 0; j < 4; ++j) acc[i][j] = fzero;

    auto v_write = [&](const uint4& vd) {
        const _Float16* ve = (const _Float16*)&vd;
#pragma unroll
        for (int j = 0; j < 8; ++j) {
            const int w  = (wo << 3) + j;
            const int fw = ((w & 7) ^ ((w >> 3) & 7)) << 4;
            *(_Float16*)(lds + B_OFF + (((w << 6) + (gg << 1)) ^ fw)) = ve[j];
        }
    };
    auto pv_compute = [&](int gc) {
        f16x8 bf[4];
#pragma unroll
        for (int ni = 0; ni < 4; ++ni) {
            const int w  = (wc << 6) + (ni << 4) + l15;
            const int fw = ((w & 7) ^ ((w >> 3) & 7)) << 4;
            bf[ni] = *(const f16x8*)(lds + B_OFF + (((w << 6) + (q4 << 4)) ^ fw));
        }
#pragma unroll
        for (int mi = 0; mi < 4; ++mi) {
            const int h = (wr << 6) + (mi << 4) + l15;
            const f16x8 afr = *(const f16x8*)(lds + P_OFF +
                (((h << 9) + ((gc + (q4 << 3)) << 1)) ^ ((h & 7) << 4)));
#pragma unroll
            for (int ni = 0; ni < 4; ++ni)
                acc[mi][ni] = __builtin_amdgcn_mfma_f32_16x16x32_f16(afr, bf[ni], acc[mi][ni], 0, 0, 0);
        }
    };

    for (int gc = 0; gc < 256; gc += 64) {
        __syncthreads();                     // P written / prior Vt reads done
        v_write(vdA);
        if (gc < 192) vdA = *(const uint4*)(Vh + vg + (size_t)(gc + 64) * 256);
        __syncthreads();
        pv_compute(gc);

        __syncthreads();
        v_write(vdB);
        if (gc < 192) vdB = *(const uint4*)(Vh + vg + (size_t)(gc + 96) * 256);
        __syncthreads();
        pv_compute(gc + 32);
    }

    // ---------------- store out (fp32) ----------------
    float* op = out + base;
#pragma unroll
    for (int mi = 0; mi < 4; ++mi) {
#pragma unroll
        for (int r = 0; r < 4; ++r) {
            const int h = (wr << 6) + (mi << 4) + (q4 << 2) + r;
#pragma unroll
            for (int ni = 0; ni < 4; ++ni) {
                const int w = (wc << 6) + (ni << 4) + l15;
                op[(h << 8) + w] = acc[mi][ni][r];
            }
        }
    }
}

// ---------------------------------------------------------------------------
extern "C" void kernel_launch(void* const* d_in, const int* in_sizes, int n_in,
                              void* d_out, int out_size, void* d_ws, size_t ws_size,
                              hipStream_t stream) {
    const float* x     = (const float*)d_in[0];
    const float* wq    = (const float*)d_in[1];
    const float* bq    = (const float*)d_in[2];
    const float* wk    = (const float*)d_in[3];
    const float* bk    = (const float*)d_in[4];
    const float* wv    = (const float*)d_in[5];
    const float* bv    = (const float*)d_in[6];
    const float* gamma = (const float*)d_in[7];
    float* out = (float*)d_out;

    // workspace: Q,K,V fp16, each 512*65536 elements = 64 MiB -> 192 MiB total
    _Float16* Qh = (_Float16*)d_ws;
    _Float16* Kh = Qh + (size_t)512 * 65536;
    _Float16* Vh = Kh + (size_t)512 * 65536;

    proj_qkv_mfma<<<512, 256, 0, stream>>>(x, wq, bq, wk, bk, wv, bv, Qh, Kh, Vh);
    attn_rowsm<<<512, 1024, 0, stream>>>(Qh, Kh, Vh, gamma, out);
}